// Round 1
// baseline (271.163 us; speedup 1.0000x reference)
//
#include <hip/hip_runtime.h>
#include <hip/hip_bf16.h>

// MoE expert pool: E=8 experts, D=512, H=2048, M=8192 tokens, top-2 routing.
// Plan: route -> per-expert packed slot lists -> grouped GEMM1 (X@Wg, X@Wv fused,
// gelu*v -> H1 bf16) -> grouped GEMM2 (H1@Wo * scale*combine_w, atomicAdd into out).

#define NEXP 8
#define DIM 512
#define HID 2048
#define MTOK 8192
#define PMAX (2*MTOK)      // exactly 2 experts per token -> 16384 pairs
#define MAXTILES 264       // sum ceil(cnt_e/64) <= 256+7, padded

typedef __bf16 bf16;
typedef __bf16 bf16x8 __attribute__((ext_vector_type(8)));
typedef float  f32x4  __attribute__((ext_vector_type(4)));

// ---- fp32 -> bf16 convert (tokens), vectorized ----
__global__ __launch_bounds__(256) void k_cvt_x(const float* __restrict__ in,
                                               bf16* __restrict__ out, int n4) {
  int i = blockIdx.x*256 + threadIdx.x;
  if (i >= n4) return;
  float4 v = ((const float4* __restrict__)in)[i];
  bf16 o[4];
  o[0]=(bf16)v.x; o[1]=(bf16)v.y; o[2]=(bf16)v.z; o[3]=(bf16)v.w;
  *(uint2*)&out[(size_t)i*4] = *(uint2*)o;
}

// ---- fp32 [E][R][C] -> bf16 [E][C][R] transpose+convert (weights) ----
__global__ __launch_bounds__(256) void k_tcvt(const float* __restrict__ in,
                                              bf16* __restrict__ out, int R, int C) {
  __shared__ __align__(16) bf16 t[64][72];
  const int e  = blockIdx.z;
  const int c0 = blockIdx.x*64, r0 = blockIdx.y*64;
  const float* __restrict__ pin = in + (size_t)e*R*C;
  bf16* __restrict__ pout = out + (size_t)e*R*C;
  const int tid = threadIdx.x;
  const int rr = tid>>4, cc4 = (tid&15)*4;
#pragma unroll
  for (int i=0;i<4;i++){
    int r = i*16 + rr;
    float4 v = *(const float4*)&pin[(size_t)(r0+r)*C + c0 + cc4];
    t[cc4+0][r]=(bf16)v.x; t[cc4+1][r]=(bf16)v.y;
    t[cc4+2][r]=(bf16)v.z; t[cc4+3][r]=(bf16)v.w;
  }
  __syncthreads();
#pragma unroll
  for (int i=0;i<4;i++){
    int c = i*16 + rr;
    *(uint2*)&pout[(size_t)(c0+c)*R + r0 + cc4] = *(uint2*)&t[c][cc4];
  }
}

// ---- routing: count tokens per expert (block-reduced atomics) ----
__global__ __launch_bounds__(256) void k_count(const float* __restrict__ disp,
                                               int* __restrict__ cnt) {
  __shared__ int lc[NEXP];
  int t = threadIdx.x;
  if (t < NEXP) lc[t] = 0;
  __syncthreads();
  int m = blockIdx.x*256 + t;
  float4 d0 = *(const float4*)&disp[(size_t)m*NEXP];
  float4 d1 = *(const float4*)&disp[(size_t)m*NEXP+4];
  if (d0.x>0.f) atomicAdd(&lc[0],1);
  if (d0.y>0.f) atomicAdd(&lc[1],1);
  if (d0.z>0.f) atomicAdd(&lc[2],1);
  if (d0.w>0.f) atomicAdd(&lc[3],1);
  if (d1.x>0.f) atomicAdd(&lc[4],1);
  if (d1.y>0.f) atomicAdd(&lc[5],1);
  if (d1.z>0.f) atomicAdd(&lc[6],1);
  if (d1.w>0.f) atomicAdd(&lc[7],1);
  __syncthreads();
  if (t < NEXP) atomicAdd(&cnt[t], lc[t]);
}

// ---- prefix over 8 experts + build tile list ----
__global__ void k_scan(const int* __restrict__ cnt, int* __restrict__ base,
                       int* __restrict__ te, int* __restrict__ trow, int* __restrict__ tn) {
  int b = 0, idx = 0;
  for (int e=0;e<NEXP;e++){
    base[e] = b;
    int c = cnt[e];
    for (int t=0; t*64 < c; t++){
      int nr = c - t*64; if (nr > 64) nr = 64;
      te[idx] = e; trow[idx] = b + t*64; tn[idx] = nr; idx++;
    }
    b += c;
  }
  for (; idx < MAXTILES; idx++) te[idx] = -1;
}

// ---- fill slot lists (slot values independent of atomic order -> deterministic) ----
__global__ __launch_bounds__(256) void k_fill(const float* __restrict__ disp,
    const float* __restrict__ comb, const float* __restrict__ scales,
    const int* __restrict__ base, int* __restrict__ fillc,
    int* __restrict__ stok, float* __restrict__ sw) {
  int m = blockIdx.x*256 + threadIdx.x;
#pragma unroll
  for (int e=0;e<NEXP;e++){
    float dv = disp[(size_t)m*NEXP + e];
    if (dv > 0.f) {
      int s = atomicAdd(&fillc[e], 1);
      int g = base[e] + s;
      stok[g] = m;
      sw[g] = comb[(size_t)m*NEXP + e] * scales[e];  // fold expert scale into weight
    }
  }
}

// ---- GEMM1: H1[p, n] = gelu(X[tok]@Wg) * (X[tok]@Wv), 64x64 tile, K=512 ----
__global__ __launch_bounds__(256) void k_gemm1(const bf16* __restrict__ Xb,
    const bf16* __restrict__ WgT, const bf16* __restrict__ WvT,
    const int* __restrict__ te, const int* __restrict__ trow, const int* __restrict__ tn,
    const int* __restrict__ stok, bf16* __restrict__ H1) {
  const int tile = blockIdx.y;
  const int e = te[tile];
  if (e < 0) return;
  const int row0 = trow[tile], nrows = tn[tile];
  const int n0 = blockIdx.x*64;
  __shared__ __align__(16) bf16 Al[64][72];
  __shared__ __align__(16) bf16 Bgl[64][72];
  __shared__ __align__(16) bf16 Bvl[64][72];
  const int tid = threadIdx.x, lane = tid&63, w = tid>>6;
  int tokR[2];
#pragma unroll
  for (int i=0;i<2;i++){
    int r = (tid + 256*i) >> 3;
    tokR[i] = stok[(r < nrows) ? (row0 + r) : row0];   // clamp garbage rows to a valid token
  }
  const bf16* __restrict__ wg = WgT + (size_t)e*HID*DIM;  // [H][D] (K contiguous)
  const bf16* __restrict__ wv = WvT + (size_t)e*HID*DIM;
  f32x4 accg[4] = {}, accv[4] = {};
  for (int k0=0; k0<DIM; k0+=64){
#pragma unroll
    for (int i=0;i<2;i++){
      int c = tid + 256*i;
      int r = c>>3, c8 = c&7;
      *(uint4*)&Al[r][c8*8]  = *(const uint4*)&Xb[(size_t)tokR[i]*DIM + k0 + c8*8];
      *(uint4*)&Bgl[r][c8*8] = *(const uint4*)&wg[(size_t)(n0+r)*DIM + k0 + c8*8];
      *(uint4*)&Bvl[r][c8*8] = *(const uint4*)&wv[(size_t)(n0+r)*DIM + k0 + c8*8];
    }
    __syncthreads();
#pragma unroll
    for (int ks=0; ks<2; ks++){
      const int ko = ks*32 + (lane>>4)*8;
      bf16x8 bg = *(bf16x8*)&Bgl[w*16 + (lane&15)][ko];
      bf16x8 bv = *(bf16x8*)&Bvl[w*16 + (lane&15)][ko];
#pragma unroll
      for (int mi=0; mi<4; mi++){
        bf16x8 a = *(bf16x8*)&Al[mi*16 + (lane&15)][ko];
        accg[mi] = __builtin_amdgcn_mfma_f32_16x16x32_bf16(a, bg, accg[mi], 0, 0, 0);
        accv[mi] = __builtin_amdgcn_mfma_f32_16x16x32_bf16(a, bv, accv[mi], 0, 0, 0);
      }
    }
    __syncthreads();
  }
  const int col = n0 + w*16 + (lane&15);
  const int rbase = (lane>>4)*4;
#pragma unroll
  for (int mi=0; mi<4; mi++){
#pragma unroll
    for (int j=0; j<4; j++){
      int r = mi*16 + rbase + j;
      if (r < nrows){
        float g = accg[mi][j], v = accv[mi][j];
        float ge = 0.5f*g*(1.f + erff(g*0.70710678118654752f));  // exact gelu
        H1[(size_t)(row0+r)*HID + col] = (bf16)(ge*v);
      }
    }
  }
}

// ---- GEMM2: out[tok] += (H1[p]@Wo) * (scale*combine_w), 64x64 tile, K=2048 ----
__global__ __launch_bounds__(256) void k_gemm2(const bf16* __restrict__ H1,
    const bf16* __restrict__ WoT,
    const int* __restrict__ te, const int* __restrict__ trow, const int* __restrict__ tn,
    const int* __restrict__ stok, const float* __restrict__ sw, float* __restrict__ out) {
  const int tile = blockIdx.y;
  const int e = te[tile];
  if (e < 0) return;
  const int row0 = trow[tile], nrows = tn[tile];
  const int n0 = blockIdx.x*64;
  __shared__ __align__(16) bf16 Al[64][72];
  __shared__ __align__(16) bf16 Bl[64][72];
  const int tid = threadIdx.x, lane = tid&63, w = tid>>6;
  const bf16* __restrict__ wo = WoT + (size_t)e*DIM*HID;  // [D][H] (K contiguous)
  f32x4 acc[4] = {};
  for (int k0=0;k0<HID;k0+=64){
#pragma unroll
    for (int i=0;i<2;i++){
      int c = tid + 256*i;
      int r = c>>3, c8 = c&7;
      int ar = (r < nrows) ? (row0 + r) : row0;  // clamp: don't read past H1
      *(uint4*)&Al[r][c8*8] = *(const uint4*)&H1[(size_t)ar*HID + k0 + c8*8];
      *(uint4*)&Bl[r][c8*8] = *(const uint4*)&wo[(size_t)(n0+r)*HID + k0 + c8*8];
    }
    __syncthreads();
#pragma unroll
    for (int ks=0;ks<2;ks++){
      const int ko = ks*32 + (lane>>4)*8;
      bf16x8 b = *(bf16x8*)&Bl[w*16 + (lane&15)][ko];
#pragma unroll
      for (int mi=0;mi<4;mi++){
        bf16x8 a = *(bf16x8*)&Al[mi*16 + (lane&15)][ko];
        acc[mi] = __builtin_amdgcn_mfma_f32_16x16x32_bf16(a, b, acc[mi], 0, 0, 0);
      }
    }
    __syncthreads();
  }
  const int col = n0 + w*16 + (lane&15);
  const int rbase = (lane>>4)*4;
#pragma unroll
  for (int mi=0;mi<4;mi++){
#pragma unroll
    for (int j=0;j<4;j++){
      int r = mi*16 + rbase + j;
      if (r < nrows){
        int slot = row0 + r;
        float v = acc[mi][j] * sw[slot];
        // exactly 2 commutative fp32 adds per element -> deterministic
        atomicAdd(&out[(size_t)stok[slot]*DIM + col], v);
      }
    }
  }
}

extern "C" void kernel_launch(void* const* d_in, const int* in_sizes, int n_in,
                              void* d_out, int out_size, void* d_ws, size_t ws_size,
                              hipStream_t stream) {
  const float* tokens = (const float*)d_in[0];
  const float* disp   = (const float*)d_in[1];
  const float* comb   = (const float*)d_in[2];
  const float* Wg     = (const float*)d_in[3];
  const float* Wv     = (const float*)d_in[4];
  const float* Wo     = (const float*)d_in[5];
  const float* scales = (const float*)d_in[6];
  float* out = (float*)d_out;

  size_t off = 0;
  char* wsb = (char*)d_ws;
  auto take = [&](size_t bytes)->char* {
    char* q = wsb + off; off += (bytes + 255) & ~(size_t)255; return q;
  };
  int*   cnt   = (int*)  take(NEXP*4);          // ws+0    (zeroed)
  int*   basee = (int*)  take(NEXP*4);          // ws+256  (zeroed, rewritten)
  int*   fillc = (int*)  take(NEXP*4);          // ws+512  (zeroed)
  int*   te    = (int*)  take(MAXTILES*4);
  int*   trow  = (int*)  take(MAXTILES*4);
  int*   tnr   = (int*)  take(MAXTILES*4);
  int*   stok  = (int*)  take((size_t)PMAX*4);
  float* sw    = (float*)take((size_t)PMAX*4);
  bf16*  Xb    = (bf16*) take((size_t)MTOK*DIM*2);
  bf16*  WgT   = (bf16*) take((size_t)NEXP*DIM*HID*2);
  bf16*  WvT   = (bf16*) take((size_t)NEXP*DIM*HID*2);
  bf16*  WoT   = (bf16*) take((size_t)NEXP*DIM*HID*2);
  bf16*  H1    = (bf16*) take((size_t)PMAX*HID*2);
  (void)ws_size; (void)in_sizes; (void)n_in;

  hipMemsetAsync(d_ws, 0, 768, stream);                              // counters
  hipMemsetAsync(d_out, 0, (size_t)out_size*sizeof(float), stream);  // atomic target

  k_cvt_x<<<dim3((MTOK*DIM/4)/256), 256, 0, stream>>>(tokens, Xb, MTOK*DIM/4);
  k_tcvt <<<dim3(HID/64, DIM/64, NEXP), 256, 0, stream>>>(Wg, WgT, DIM, HID);
  k_tcvt <<<dim3(HID/64, DIM/64, NEXP), 256, 0, stream>>>(Wv, WvT, DIM, HID);
  k_tcvt <<<dim3(DIM/64, HID/64, NEXP), 256, 0, stream>>>(Wo, WoT, HID, DIM);
  k_count<<<dim3(MTOK/256), 256, 0, stream>>>(disp, cnt);
  k_scan <<<1, 1, 0, stream>>>(cnt, basee, te, trow, tnr);
  k_fill <<<dim3(MTOK/256), 256, 0, stream>>>(disp, comb, scales, basee, fillc, stok, sw);
  k_gemm1<<<dim3(HID/64, MAXTILES), 256, 0, stream>>>(Xb, WgT, WvT, te, trow, tnr, stok, H1);
  k_gemm2<<<dim3(DIM/64, MAXTILES), 256, 0, stream>>>(H1, WoT, te, trow, tnr, stok, sw, out);
}